// Round 5
// baseline (255.475 us; speedup 1.0000x reference)
//
#include <hip/hip_runtime.h>
#include <hip/hip_bf16.h>

#define RREL 4
#define DIM 256
#define KDIM 1280      // 4*DIM (means) + DIM (self)
#define KMEAN 1024     // means-only K extent of Y
#define BCAP 32        // bucket capacity per (r,dst) segment

__device__ __forceinline__ float bf2f(unsigned short u) {
    union { unsigned int i; float f; } z; z.i = ((unsigned int)u) << 16; return z.f;
}
__device__ __forceinline__ unsigned short f2bf(float f) {
    __hip_bfloat16 h = __float2bfloat16(f);
    return *(unsigned short*)&h;
}

typedef __attribute__((ext_vector_type(8))) short bf16x8;
typedef __attribute__((ext_vector_type(8))) unsigned short u16x8;
typedef __attribute__((ext_vector_type(4))) float f32x4;
typedef __attribute__((ext_vector_type(4))) float fx4;

// ---------------- fused prep: bucket-scatter + x->bf16 cast + W0 transpose ----------

__global__ __launch_bounds__(256)
void prep(const int* __restrict__ etype, const int* __restrict__ src,
          const int* __restrict__ dst,
          int* __restrict__ counts, int* __restrict__ bucket, int N, int E,
          const float* __restrict__ x, __hip_bfloat16* __restrict__ xb, int n4,
          const float* __restrict__ W0, const float* __restrict__ root0,
          __hip_bfloat16* __restrict__ WT,
          int eb, int cb) {
    int b = blockIdx.x;
    if (b < eb) {                       // count + scatter into buckets
        int e = b * 256 + threadIdx.x;
        if (e < E) {
            int seg = etype[e] * N + dst[e];
            int p = atomicAdd(&counts[seg], 1);
            if (p < BCAP) bucket[(size_t)seg * BCAP + p] = src[e];
        }
    } else if (b < eb + cb) {           // cast x -> bf16
        int i = (b - eb) * 256 + threadIdx.x;
        if (i < n4) {
            fx4 v = *((const fx4*)x + i);
            ushort4 u = make_ushort4(f2bf(v.x), f2bf(v.y), f2bf(v.z), f2bf(v.w));
            ((ushort4*)xb)[i] = u;
        }
    } else {                            // WT[n=0..255][k=0..1279] n-major (layer 0)
        __shared__ float tile[32][33];
        int q = b - eb - cb;            // 0..319
        int nblk = q / 40;              // 0..7   (n0 over 256)
        int kblk = q - nblk * 40;       // 0..39  (k0 over 1280)
        int k0 = kblk * 32, n0 = nblk * 32;
        int tx = threadIdx.x & 31, ty = threadIdx.x >> 5;   // 32x8
        const float* srcp;
        int kbase;
        if (k0 < RREL * DIM) { srcp = W0; kbase = k0; } else { srcp = root0; kbase = k0 - RREL * DIM; }
#pragma unroll
        for (int j = 0; j < 4; j++) {
            int k = kbase + ty + j * 8;
            tile[ty + j * 8][tx] = srcp[(size_t)k * DIM + n0 + tx];
        }
        __syncthreads();
#pragma unroll
        for (int j = 0; j < 4; j++) {
            int n = n0 + ty + j * 8;
            WT[(size_t)n * KDIM + k0 + tx] = __float2bfloat16(tile[tx][ty + j * 8]);
        }
    }
}

// ---------------- aggregation (layer 0): Y[i,r*256:+256] = mean_r(xb)  (bf16) ----------------
// Y write nontemporal: written once, read once by gemm; keeps xb gather table in L2.
// Blocks >= ab: per-edge weight scatter w(s,r) += 1/cnt(r,dst) for the collapsed layer 1.

__global__ __launch_bounds__(256)
void aggregate(const __hip_bfloat16* __restrict__ feat, const int* __restrict__ counts,
               const int* __restrict__ bucket, __hip_bfloat16* __restrict__ Y, int N,
               const int* __restrict__ etype, const int* __restrict__ srcv,
               const int* __restrict__ dstv, float* __restrict__ wsr, int E, int ab) {
    if ((int)blockIdx.x >= ab) {        // edge-weight pass
        int e = (blockIdx.x - ab) * 256 + threadIdx.x;
        if (e < E) {
            int r = etype[e];
            int seg = r * N + dstv[e];
            float sc = 1.f / (float)counts[seg];
            atomicAdd(&wsr[(size_t)srcv[e] * RREL + r], sc);
        }
        return;
    }
    int r = threadIdx.x >> 6, lane = threadIdx.x & 63;
    int h = lane >> 5, li = lane & 31;
    int i = blockIdx.x * 2 + h;
    if (i >= N) return;
    int seg = r * N + i;
    int cnt = min(counts[seg], BCAP);
    const unsigned short* fu = (const unsigned short*)feat;
    const int* bk = bucket + (size_t)seg * BCAP;
    float a[8] = {};
    for (int k = 0; k < cnt; k += 4) {
        int4 q = *(const int4*)(bk + k);           // 16B-aligned
        float m1 = (k + 1 < cnt) ? 1.f : 0.f;
        float m2 = (k + 2 < cnt) ? 1.f : 0.f;
        float m3 = (k + 3 < cnt) ? 1.f : 0.f;
        int i0 = q.x;
        int i1 = m1 ? q.y : q.x;                   // clamp to a valid row address
        int i2 = m2 ? q.z : q.x;
        int i3 = m3 ? q.w : q.x;
        u16x8 v0 = *(const u16x8*)(fu + (size_t)i0 * DIM + li * 8);
        u16x8 v1 = *(const u16x8*)(fu + (size_t)i1 * DIM + li * 8);
        u16x8 v2 = *(const u16x8*)(fu + (size_t)i2 * DIM + li * 8);
        u16x8 v3 = *(const u16x8*)(fu + (size_t)i3 * DIM + li * 8);
#pragma unroll
        for (int j = 0; j < 8; j++)
            a[j] += bf2f(v0[j]) + m1 * bf2f(v1[j]) + m2 * bf2f(v2[j]) + m3 * bf2f(v3[j]);
    }
    float inv = (cnt > 0) ? 1.f / (float)cnt : 0.f;
    u16x8 u;
#pragma unroll
    for (int j = 0; j < 8; j++) u[j] = f2bf(a[j] * inv);
    __builtin_nontemporal_store(u,
        (u16x8*)((unsigned short*)Y + (size_t)i * KMEAN + r * DIM + li * 8));
}

// ---------------- MFMA GEMM (layer 0) + fused collapsed-layer-1 colsum epilogue ----------
// R4 counters: MfmaUtil 7.5%, VALUBusy 4.9%, 507 GB/s, occupancy 23% -> latency-bound:
// __syncthreads' implied vmcnt(0) drained the global_load_lds queue every K-step, and
// 80 KB LDS meant 1 block/CU -> lockstep waves + 57-block serial tail.
// Fix: 256 threads, BK=32 (40 KB LDS -> 4 blocks/CU, all 313 blocks co-resident) and a
// counted-vmcnt pipeline: issue tile k+1's 5 loads, wait vmcnt(5) (never 0 mid-loop),
// raw s_barrier. Prefetch loads stay in flight across barriers (T4).
//   sv[r*256+c] += sum_rows wsr[row][r] * relu_h1[row][c]   (r=0..3)
//   sv[4*256+c] += sum_rows relu_h1[row][c]

#define BMg 64
#define BKg 32

__global__ __launch_bounds__(256)
void gemm_mfma(const __hip_bfloat16* __restrict__ A,     // [Mpad, 1024] means
               const __hip_bfloat16* __restrict__ Aself, // [Mpad, 256] feature table
               const __hip_bfloat16* __restrict__ Bt,    // [256, 1280] n-major
               const float* __restrict__ bias,           // [256]
               const float* __restrict__ wsr,            // [N, 4] edge weights
               float* __restrict__ sv,                   // [5*256] output sums
               int Nrows) {
    __shared__ short As[2][BMg * BKg];       // 2 x 4 KB
    __shared__ short Bs[2][DIM * BKg];       // 2 x 16 KB   (40 KB total)
    int t = threadIdx.x;
    int lane = t & 63;
    int w = t >> 6;                           // wave 0..3 -> col quarter
    size_t row0 = (size_t)blockIdx.x * BMg;

    const unsigned short* Ag = (const unsigned short*)A;
    const unsigned short* Sg = (const unsigned short*)Aself;
    const unsigned short* Bg = (const unsigned short*)Bt;

    float bb[4];
#pragma unroll
    for (int ni = 0; ni < 4; ni++) bb[ni] = bias[w * 64 + ni * 16 + (lane & 15)];

    f32x4 acc[4][4] = {};

    // 5 global_load_lds per thread per tile (A:1, B:4) -> steady-state vmcnt(5)
    auto issue_tile = [&](int k0, short* as, short* bs) {
        const unsigned short* Abase;
        int kk, stride;
        if (k0 < KMEAN) { Abase = Ag; kk = k0; stride = KMEAN; }
        else            { Abase = Sg; kk = k0 - KMEAN; stride = DIM; }
        {                                          // A: 256 chunks of 16B, 1/thread
            int c = t;
            int r = c >> 2, pl = c & 3, pg = pl ^ (r & 3);
            const unsigned short* ga = Abase + (row0 + r) * stride + kk + pg * 8;
            __builtin_amdgcn_global_load_lds(
                (const __attribute__((address_space(1))) void*)ga,
                (__attribute__((address_space(3))) void*)((char*)as + c * 16),
                16, 0, 0);
        }
#pragma unroll
        for (int h = 0; h < 4; h++) {              // B: 1024 chunks of 16B, 4/thread
            int c = t + h * 256;
            int r = c >> 2, pl = c & 3, pg = pl ^ (r & 3);
            const unsigned short* gb = Bg + (size_t)r * KDIM + k0 + pg * 8;
            __builtin_amdgcn_global_load_lds(
                (const __attribute__((address_space(1))) void*)gb,
                (__attribute__((address_space(3))) void*)((char*)bs + c * 16),
                16, 0, 0);
        }
    };

    issue_tile(0, As[0], Bs[0]);
    int cur = 0;
    for (int k0 = 0; k0 < KDIM; k0 += BKg) {
        if (k0 + BKg < KDIM) {
            // issue next tile BEFORE waiting on this one: loads stay in flight
            // across the barrier (counted vmcnt, never 0 mid-loop)
            issue_tile(k0 + BKg, As[cur ^ 1], Bs[cur ^ 1]);
            asm volatile("s_waitcnt vmcnt(5)" ::: "memory");
        } else {
            asm volatile("s_waitcnt vmcnt(0)" ::: "memory");
        }
        __builtin_amdgcn_s_barrier();              // all waves' tile-k data visible
        __builtin_amdgcn_sched_barrier(0);         // no ds_read hoisting (rule 18)
        const short* as = As[cur];
        const short* bs = Bs[cur];
        int p = lane >> 4;                         // 16B part 0..3
        bf16x8 af[4], bfr[4];
#pragma unroll
        for (int mi = 0; mi < 4; mi++) {
            int m = mi * 16 + (lane & 15);
            af[mi] = *(const bf16x8*)&as[m * 32 + ((p ^ (m & 3)) * 8)];
        }
#pragma unroll
        for (int ni = 0; ni < 4; ni++) {
            int n = w * 64 + ni * 16 + (lane & 15);
            bfr[ni] = *(const bf16x8*)&bs[n * 32 + ((p ^ (n & 3)) * 8)];
        }
#pragma unroll
        for (int mi = 0; mi < 4; mi++)
#pragma unroll
            for (int ni = 0; ni < 4; ni++)
                acc[mi][ni] = __builtin_amdgcn_mfma_f32_16x16x32_bf16(af[mi], bfr[ni], acc[mi][ni], 0, 0, 0);
        __builtin_amdgcn_s_barrier();              // buf[cur] fully read -> reusable
        __builtin_amdgcn_sched_barrier(0);         // no issue-hoisting above barrier
        cur ^= 1;
    }

    // Fused epilogue. C/D layout: col=lane&15, row=(lane>>4)*4+j  [m89-verified].
    // Each wave covers rows row0..row0+63 exactly once (mi,j,lane>>4); waves differ
    // in cols (w). Reduce over lane bits 4,5 -> lanes 0..15 atomic.
    float a[4][5];
#pragma unroll
    for (int ni = 0; ni < 4; ni++)
#pragma unroll
        for (int s = 0; s < 5; s++) a[ni][s] = 0.f;

#pragma unroll
    for (int mi = 0; mi < 4; mi++) {
#pragma unroll
        for (int j = 0; j < 4; j++) {
            size_t row = row0 + mi * 16 + (lane >> 4) * 4 + j;
            if (row < (size_t)Nrows) {             // poison rows never touched
                fx4 wv = *(const fx4*)(wsr + row * RREL);
#pragma unroll
                for (int ni = 0; ni < 4; ni++) {
                    float v = fmaxf(acc[mi][ni][j] + bb[ni], 0.f);   // relu BEFORE weighting
                    a[ni][4] += v;
                    a[ni][0] += wv.x * v;
                    a[ni][1] += wv.y * v;
                    a[ni][2] += wv.z * v;
                    a[ni][3] += wv.w * v;
                }
            }
        }
    }
#pragma unroll
    for (int ni = 0; ni < 4; ni++) {
        int col = w * 64 + ni * 16 + (lane & 15);
#pragma unroll
        for (int s = 0; s < 5; s++) {
            float v = a[ni][s];
            v += __shfl_xor(v, 16, 64);
            v += __shfl_xor(v, 32, 64);
            if ((lane >> 4) == 0) atomicAdd(&sv[s * DIM + col], v);
        }
    }
}

// ---------------- collapsed layer 1 GEMV + fused linear head ----------------
// g = sv @ Wcat1 + N*b1. 8 k/block (160 blocks). Last block computes the head.

__global__ __launch_bounds__(256)
void gemv_final(const float* __restrict__ sv, const float* __restrict__ W1,
                const float* __restrict__ root1, const float* __restrict__ b1,
                int N, float* __restrict__ g, int* __restrict__ done,
                const float* __restrict__ lw, const float* __restrict__ lb,
                float* __restrict__ out, int nblk) {
    int t = threadIdx.x;
    int kk0 = blockIdx.x * 8;
    float acc = 0.f;
#pragma unroll
    for (int u = 0; u < 8; u++) {
        int kk = kk0 + u;
        int r = kk >> 8;                 // 0..4
        int k = kk & 255;
        const float* row = (r < RREL) ? (W1 + ((size_t)r * DIM + k) * DIM)
                                      : (root1 + (size_t)k * DIM);
        acc += sv[kk] * row[t];
    }
    if (blockIdx.x == 0) acc += (float)N * b1[t];
    atomicAdd(&g[t], acc);
    __threadfence();
    __shared__ int amLast;
    if (t == 0) amLast = (atomicAdd(done, 1) == nblk - 1);
    __syncthreads();
    if (!amLast) return;
    float gv = atomicAdd(&g[t], 0.f);    // device-scope coherent read
    __shared__ float s0[256], s1[256];
    s0[t] = gv * lw[t * 2 + 0];
    s1[t] = gv * lw[t * 2 + 1];
    __syncthreads();
    for (int off = 128; off > 0; off >>= 1) {
        if (t < off) { s0[t] += s0[t + off]; s1[t] += s1[t + off]; }
        __syncthreads();
    }
    if (t == 0) { out[0] = s0[0] + lb[0]; out[1] = s1[0] + lb[1]; }
}

// ---------------- launch ----------------

static inline char* align_up(char* p, size_t a) {
    return (char*)(((uintptr_t)p + (a - 1)) & ~(uintptr_t)(a - 1));
}

extern "C" void kernel_launch(void* const* d_in, const int* in_sizes, int n_in,
                              void* d_out, int out_size, void* d_ws, size_t ws_size,
                              hipStream_t stream) {
    const float* x     = (const float*)d_in[0];
    const int*   eidx  = (const int*)d_in[1];
    const int*   etype = (const int*)d_in[2];
    const float* W0    = (const float*)d_in[4];
    const float* root0 = (const float*)d_in[5];
    const float* b0    = (const float*)d_in[6];
    const float* W1    = (const float*)d_in[7];
    const float* root1 = (const float*)d_in[8];
    const float* b1    = (const float*)d_in[9];
    const float* lin_w = (const float*)d_in[10];
    const float* lin_b = (const float*)d_in[11];
    float* out = (float*)d_out;

    const int N = in_sizes[0] / DIM;
    const int E = in_sizes[2];
    const int RN = RREL * N;
    const int* src = eidx;
    const int* dst = eidx + E;

    const int gx = (N + BMg - 1) / BMg;
    const int Mpad = gx * BMg;

    char* w = (char*)d_ws;
    int*   counts = (int*)w;   w += (size_t)RN * 4;
    float* wsr    = (float*)w; w += (size_t)N * RREL * 4;
    float* sv     = (float*)w; w += (size_t)5 * DIM * 4;
    float* g      = (float*)w; w += 256 * 4;
    int*   done   = (int*)w;   w += 256;            // padded counter slot
    size_t zero_bytes = (size_t)RN * 4 + (size_t)N * RREL * 4 + 5 * DIM * 4 + 256 * 4 + 256;
    int* bucket = (int*)w; w += (size_t)RN * BCAP * 4;
    w = align_up(w, 16);
    __hip_bfloat16* WT = (__hip_bfloat16*)w; w += (size_t)DIM * KDIM * 2;
    w = align_up(w, 16);
    __hip_bfloat16* Y  = (__hip_bfloat16*)w; w += (size_t)Mpad * KMEAN * 2;
    __hip_bfloat16* xb = (__hip_bfloat16*)w; w += (size_t)Mpad * DIM * 2;

    hipMemsetAsync(counts, 0, zero_bytes, stream);

    int eb = (E + 255) / 256;                 // scatter / edge-weight blocks
    int n4 = N * DIM / 4;
    int cb = (n4 + 255) / 256;                // cast blocks
    int wb = (KDIM / 32) * (DIM / 32);        // W0-transpose blocks (40*8)

    prep<<<eb + cb + wb, 256, 0, stream>>>(etype, src, dst, counts, bucket, N, E,
                                           x, xb, n4, W0, root0, WT, eb, cb);

    int ab = (N + 1) / 2;
    // layer 0 aggregate (+ fused edge-weight pass for collapsed layer 1)
    aggregate<<<ab + eb, 256, 0, stream>>>(xb, counts, bucket, Y, N,
                                           etype, src, dst, wsr, E, ab);
    // layer 0 GEMM with fused layer-1 colsum epilogue -> sv
    gemm_mfma<<<gx, 256, 0, stream>>>(Y, xb, WT, b0, wsr, sv, N);
    // collapsed layer 1 GEMV + fused linear head -> out
    int gvb = KDIM / 8;
    gemv_final<<<gvb, 256, 0, stream>>>(sv, W1, root1, b1, N, g, done,
                                        lin_w, lin_b, out, gvb);
}

// Round 6
// 242.026 us; speedup vs baseline: 1.0556x; 1.0556x over previous
//
#include <hip/hip_runtime.h>
#include <hip/hip_bf16.h>

#define RREL 4
#define DIM 256
#define KDIM 1280      // 4*DIM (means) + DIM (self)
#define KMEAN 1024     // means-only K extent of Y
#define BCAP 32        // bucket capacity per (r,dst) segment

__device__ __forceinline__ float bf2f(unsigned short u) {
    union { unsigned int i; float f; } z; z.i = ((unsigned int)u) << 16; return z.f;
}
__device__ __forceinline__ unsigned short f2bf(float f) {
    __hip_bfloat16 h = __float2bfloat16(f);
    return *(unsigned short*)&h;
}

typedef __attribute__((ext_vector_type(8))) short bf16x8;
typedef __attribute__((ext_vector_type(8))) unsigned short u16x8;
typedef __attribute__((ext_vector_type(4))) float f32x4;
typedef __attribute__((ext_vector_type(4))) float fx4;

// ---------------- fused prep: bucket-scatter + x->bf16 cast + W0 transpose ----------

__global__ __launch_bounds__(256)
void prep(const int* __restrict__ etype, const int* __restrict__ src,
          const int* __restrict__ dst,
          int* __restrict__ counts, int* __restrict__ bucket, int N, int E,
          const float* __restrict__ x, __hip_bfloat16* __restrict__ xb, int n4,
          const float* __restrict__ W0, const float* __restrict__ root0,
          __hip_bfloat16* __restrict__ WT,
          int eb, int cb) {
    int b = blockIdx.x;
    if (b < eb) {                       // count + scatter into buckets
        int e = b * 256 + threadIdx.x;
        if (e < E) {
            int seg = etype[e] * N + dst[e];
            int p = atomicAdd(&counts[seg], 1);
            if (p < BCAP) bucket[(size_t)seg * BCAP + p] = src[e];
        }
    } else if (b < eb + cb) {           // cast x -> bf16
        int i = (b - eb) * 256 + threadIdx.x;
        if (i < n4) {
            fx4 v = *((const fx4*)x + i);
            ushort4 u = make_ushort4(f2bf(v.x), f2bf(v.y), f2bf(v.z), f2bf(v.w));
            ((ushort4*)xb)[i] = u;
        }
    } else {                            // WT[n=0..255][k=0..1279] n-major (layer 0)
        __shared__ float tile[32][33];
        int q = b - eb - cb;            // 0..319
        int nblk = q / 40;              // 0..7   (n0 over 256)
        int kblk = q - nblk * 40;       // 0..39  (k0 over 1280)
        int k0 = kblk * 32, n0 = nblk * 32;
        int tx = threadIdx.x & 31, ty = threadIdx.x >> 5;   // 32x8
        const float* srcp;
        int kbase;
        if (k0 < RREL * DIM) { srcp = W0; kbase = k0; } else { srcp = root0; kbase = k0 - RREL * DIM; }
#pragma unroll
        for (int j = 0; j < 4; j++) {
            int k = kbase + ty + j * 8;
            tile[ty + j * 8][tx] = srcp[(size_t)k * DIM + n0 + tx];
        }
        __syncthreads();
#pragma unroll
        for (int j = 0; j < 4; j++) {
            int n = n0 + ty + j * 8;
            WT[(size_t)n * KDIM + k0 + tx] = __float2bfloat16(tile[tx][ty + j * 8]);
        }
    }
}

// ---------------- aggregation (layer 0): Y[i,r*256:+256] = mean_r(xb)  (bf16) ----------------
// Y write nontemporal: written once, read once by gemm; keeps xb gather table in L2.
// Blocks >= ab: per-edge weight scatter w(s,r) += 1/cnt(r,dst) for the collapsed layer 1.

__global__ __launch_bounds__(256)
void aggregate(const __hip_bfloat16* __restrict__ feat, const int* __restrict__ counts,
               const int* __restrict__ bucket, __hip_bfloat16* __restrict__ Y, int N,
               const int* __restrict__ etype, const int* __restrict__ srcv,
               const int* __restrict__ dstv, float* __restrict__ wsr, int E, int ab) {
    if ((int)blockIdx.x >= ab) {        // edge-weight pass
        int e = (blockIdx.x - ab) * 256 + threadIdx.x;
        if (e < E) {
            int r = etype[e];
            int seg = r * N + dstv[e];
            float sc = 1.f / (float)counts[seg];
            atomicAdd(&wsr[(size_t)srcv[e] * RREL + r], sc);
        }
        return;
    }
    int r = threadIdx.x >> 6, lane = threadIdx.x & 63;
    int h = lane >> 5, li = lane & 31;
    int i = blockIdx.x * 2 + h;
    if (i >= N) return;
    int seg = r * N + i;
    int cnt = min(counts[seg], BCAP);
    const unsigned short* fu = (const unsigned short*)feat;
    const int* bk = bucket + (size_t)seg * BCAP;
    float a[8] = {};
    for (int k = 0; k < cnt; k += 4) {
        int4 q = *(const int4*)(bk + k);           // 16B-aligned
        float m1 = (k + 1 < cnt) ? 1.f : 0.f;
        float m2 = (k + 2 < cnt) ? 1.f : 0.f;
        float m3 = (k + 3 < cnt) ? 1.f : 0.f;
        int i0 = q.x;
        int i1 = m1 ? q.y : q.x;                   // clamp to a valid row address
        int i2 = m2 ? q.z : q.x;
        int i3 = m3 ? q.w : q.x;
        u16x8 v0 = *(const u16x8*)(fu + (size_t)i0 * DIM + li * 8);
        u16x8 v1 = *(const u16x8*)(fu + (size_t)i1 * DIM + li * 8);
        u16x8 v2 = *(const u16x8*)(fu + (size_t)i2 * DIM + li * 8);
        u16x8 v3 = *(const u16x8*)(fu + (size_t)i3 * DIM + li * 8);
#pragma unroll
        for (int j = 0; j < 8; j++)
            a[j] += bf2f(v0[j]) + m1 * bf2f(v1[j]) + m2 * bf2f(v2[j]) + m3 * bf2f(v3[j]);
    }
    float inv = (cnt > 0) ? 1.f / (float)cnt : 0.f;
    u16x8 u;
#pragma unroll
    for (int j = 0; j < 8; j++) u[j] = f2bf(a[j] * inv);
    __builtin_nontemporal_store(u,
        (u16x8*)((unsigned short*)Y + (size_t)i * KMEAN + r * DIM + li * 8));
}

// ---------------- MFMA GEMM (layer 0) + fused collapsed-layer-1 colsum epilogue ----------
// R5 counters: gemm 50us, MfmaUtil 9.4%, occupancy 11% (1 block/CU -> 4 lockstep waves,
// no cross-block TLP to cover load latency), 1.6M LDS bank conflicts (BK=32's narrowed
// swizzle). Fix: BM=64 x BN=128 (N-split x2 -> 626 blocks), BK=64, 48 KB LDS
// -> 3 blocks/CU capacity, all blocks co-resident: independent blocks overlap each
// other's vmcnt/barrier stalls. 8-part XOR swizzle = the R3/R4-measured-zero-conflict
// geometry. Counted vmcnt(6): next tile's 6 loads stay in flight across the barrier.
// B-panel duplication across n-halves is free (WT 0.66 MB, L2-resident); Y is M-split
// (no duplication); block pairs (2m, 2m+1) share Y rows for L2 locality.
//   sv[r*256+c] += sum_rows wsr[row][r] * relu_h1[row][c]   (r=0..3)
//   sv[4*256+c] += sum_rows relu_h1[row][c]

#define BMg 64
#define BNg 128
#define BKg 64

__global__ __launch_bounds__(256)
void gemm_mfma(const __hip_bfloat16* __restrict__ A,     // [Mpad, 1024] means
               const __hip_bfloat16* __restrict__ Aself, // [Mpad, 256] feature table
               const __hip_bfloat16* __restrict__ Bt,    // [256, 1280] n-major
               const float* __restrict__ bias,           // [256]
               const float* __restrict__ wsr,            // [N, 4] edge weights
               float* __restrict__ sv,                   // [5*256] output sums
               int Nrows) {
    __shared__ short As[2][BMg * BKg];       // 2 x 8 KB
    __shared__ short Bs[2][BNg * BKg];       // 2 x 16 KB   (48 KB total)
    int t = threadIdx.x;
    int lane = t & 63;
    int w = t >> 6;                           // wave 0..3 -> 32-col slice
    int nh = blockIdx.x & 1;                  // n-half 0..1
    size_t row0 = (size_t)(blockIdx.x >> 1) * BMg;
    int ncol0 = nh * BNg;                     // global col base of this block

    const unsigned short* Ag = (const unsigned short*)A;
    const unsigned short* Sg = (const unsigned short*)Aself;
    const unsigned short* Bg = (const unsigned short*)Bt;

    float bb[2];
#pragma unroll
    for (int ni = 0; ni < 2; ni++) bb[ni] = bias[ncol0 + w * 32 + ni * 16 + (lane & 15)];

    f32x4 acc[4][2] = {};

    // 6 global_load_lds per thread per tile (A:2, B:4) -> steady-state vmcnt(6)
    auto issue_tile = [&](int k0, short* as, short* bs) {
        const unsigned short* Abase;
        int kk, stride;
        if (k0 < KMEAN) { Abase = Ag; kk = k0; stride = KMEAN; }
        else            { Abase = Sg; kk = k0 - KMEAN; stride = DIM; }
#pragma unroll
        for (int h = 0; h < 2; h++) {              // A: 512 chunks of 16B, 2/thread
            int c = t + h * 256;
            int r = c >> 3, pl = c & 7, pg = pl ^ (r & 7);
            const unsigned short* ga = Abase + (row0 + r) * stride + kk + pg * 8;
            __builtin_amdgcn_global_load_lds(
                (const __attribute__((address_space(1))) void*)ga,
                (__attribute__((address_space(3))) void*)((char*)as + c * 16),
                16, 0, 0);
        }
#pragma unroll
        for (int h = 0; h < 4; h++) {              // B: 1024 chunks of 16B, 4/thread
            int c = t + h * 256;
            int r = c >> 3, pl = c & 7, pg = pl ^ (r & 7);
            const unsigned short* gb = Bg + (size_t)(ncol0 + r) * KDIM + k0 + pg * 8;
            __builtin_amdgcn_global_load_lds(
                (const __attribute__((address_space(1))) void*)gb,
                (__attribute__((address_space(3))) void*)((char*)bs + c * 16),
                16, 0, 0);
        }
    };

    issue_tile(0, As[0], Bs[0]);
    int cur = 0;
    for (int k0 = 0; k0 < KDIM; k0 += BKg) {
        if (k0 + BKg < KDIM) {
            // issue next tile BEFORE waiting on this one: loads stay in flight
            // across the barrier (counted vmcnt, never 0 mid-loop)
            issue_tile(k0 + BKg, As[cur ^ 1], Bs[cur ^ 1]);
            asm volatile("s_waitcnt vmcnt(6)" ::: "memory");
        } else {
            asm volatile("s_waitcnt vmcnt(0)" ::: "memory");
        }
        __builtin_amdgcn_s_barrier();              // all waves' tile-k data visible
        __builtin_amdgcn_sched_barrier(0);         // no ds_read hoisting (rule 18)
        const short* as = As[cur];
        const short* bs = Bs[cur];
#pragma unroll
        for (int ks = 0; ks < 2; ks++) {
            int p = ks * 4 + (lane >> 4);          // 16B part index 0..7
            bf16x8 af[4], bfr[2];
#pragma unroll
            for (int mi = 0; mi < 4; mi++) {
                int m = mi * 16 + (lane & 15);
                af[mi] = *(const bf16x8*)&as[m * 64 + ((p ^ (m & 7)) * 8)];
            }
#pragma unroll
            for (int ni = 0; ni < 2; ni++) {
                int n = w * 32 + ni * 16 + (lane & 15);
                bfr[ni] = *(const bf16x8*)&bs[n * 64 + ((p ^ (n & 7)) * 8)];
            }
#pragma unroll
            for (int mi = 0; mi < 4; mi++)
#pragma unroll
                for (int ni = 0; ni < 2; ni++)
                    acc[mi][ni] = __builtin_amdgcn_mfma_f32_16x16x32_bf16(af[mi], bfr[ni], acc[mi][ni], 0, 0, 0);
        }
        __builtin_amdgcn_s_barrier();              // buf[cur] fully read -> reusable
        __builtin_amdgcn_sched_barrier(0);         // no issue-hoisting above barrier
        cur ^= 1;
    }

    // Fused epilogue. C/D layout: col=lane&15, row=(lane>>4)*4+j  [m89-verified].
    // Each wave covers rows row0..row0+63 exactly once (mi,j,lane>>4); waves differ
    // in cols (w). Reduce over lane bits 4,5 -> lanes 0..15 atomic.
    float a[2][5];
#pragma unroll
    for (int ni = 0; ni < 2; ni++)
#pragma unroll
        for (int s = 0; s < 5; s++) a[ni][s] = 0.f;

#pragma unroll
    for (int mi = 0; mi < 4; mi++) {
#pragma unroll
        for (int j = 0; j < 4; j++) {
            size_t row = row0 + mi * 16 + (lane >> 4) * 4 + j;
            if (row < (size_t)Nrows) {             // poison rows never touched
                fx4 wv = *(const fx4*)(wsr + row * RREL);
#pragma unroll
                for (int ni = 0; ni < 2; ni++) {
                    float v = fmaxf(acc[mi][ni][j] + bb[ni], 0.f);   // relu BEFORE weighting
                    a[ni][4] += v;
                    a[ni][0] += wv.x * v;
                    a[ni][1] += wv.y * v;
                    a[ni][2] += wv.z * v;
                    a[ni][3] += wv.w * v;
                }
            }
        }
    }
#pragma unroll
    for (int ni = 0; ni < 2; ni++) {
        int col = ncol0 + w * 32 + ni * 16 + (lane & 15);
#pragma unroll
        for (int s = 0; s < 5; s++) {
            float v = a[ni][s];
            v += __shfl_xor(v, 16, 64);
            v += __shfl_xor(v, 32, 64);
            if ((lane >> 4) == 0) atomicAdd(&sv[s * DIM + col], v);
        }
    }
}

// ---------------- collapsed layer 1 GEMV + fused linear head ----------------
// g = sv @ Wcat1 + N*b1. 8 k/block (160 blocks). Last block computes the head.

__global__ __launch_bounds__(256)
void gemv_final(const float* __restrict__ sv, const float* __restrict__ W1,
                const float* __restrict__ root1, const float* __restrict__ b1,
                int N, float* __restrict__ g, int* __restrict__ done,
                const float* __restrict__ lw, const float* __restrict__ lb,
                float* __restrict__ out, int nblk) {
    int t = threadIdx.x;
    int kk0 = blockIdx.x * 8;
    float acc = 0.f;
#pragma unroll
    for (int u = 0; u < 8; u++) {
        int kk = kk0 + u;
        int r = kk >> 8;                 // 0..4
        int k = kk & 255;
        const float* row = (r < RREL) ? (W1 + ((size_t)r * DIM + k) * DIM)
                                      : (root1 + (size_t)k * DIM);
        acc += sv[kk] * row[t];
    }
    if (blockIdx.x == 0) acc += (float)N * b1[t];
    atomicAdd(&g[t], acc);
    __threadfence();
    __shared__ int amLast;
    if (t == 0) amLast = (atomicAdd(done, 1) == nblk - 1);
    __syncthreads();
    if (!amLast) return;
    float gv = atomicAdd(&g[t], 0.f);    // device-scope coherent read
    __shared__ float s0[256], s1[256];
    s0[t] = gv * lw[t * 2 + 0];
    s1[t] = gv * lw[t * 2 + 1];
    __syncthreads();
    for (int off = 128; off > 0; off >>= 1) {
        if (t < off) { s0[t] += s0[t + off]; s1[t] += s1[t + off]; }
        __syncthreads();
    }
    if (t == 0) { out[0] = s0[0] + lb[0]; out[1] = s1[0] + lb[1]; }
}

// ---------------- launch ----------------

static inline char* align_up(char* p, size_t a) {
    return (char*)(((uintptr_t)p + (a - 1)) & ~(uintptr_t)(a - 1));
}

extern "C" void kernel_launch(void* const* d_in, const int* in_sizes, int n_in,
                              void* d_out, int out_size, void* d_ws, size_t ws_size,
                              hipStream_t stream) {
    const float* x     = (const float*)d_in[0];
    const int*   eidx  = (const int*)d_in[1];
    const int*   etype = (const int*)d_in[2];
    const float* W0    = (const float*)d_in[4];
    const float* root0 = (const float*)d_in[5];
    const float* b0    = (const float*)d_in[6];
    const float* W1    = (const float*)d_in[7];
    const float* root1 = (const float*)d_in[8];
    const float* b1    = (const float*)d_in[9];
    const float* lin_w = (const float*)d_in[10];
    const float* lin_b = (const float*)d_in[11];
    float* out = (float*)d_out;

    const int N = in_sizes[0] / DIM;
    const int E = in_sizes[2];
    const int RN = RREL * N;
    const int* src = eidx;
    const int* dst = eidx + E;

    const int gx = (N + BMg - 1) / BMg;
    const int Mpad = gx * BMg;

    char* w = (char*)d_ws;
    int*   counts = (int*)w;   w += (size_t)RN * 4;
    float* wsr    = (float*)w; w += (size_t)N * RREL * 4;
    float* sv     = (float*)w; w += (size_t)5 * DIM * 4;
    float* g      = (float*)w; w += 256 * 4;
    int*   done   = (int*)w;   w += 256;            // padded counter slot
    size_t zero_bytes = (size_t)RN * 4 + (size_t)N * RREL * 4 + 5 * DIM * 4 + 256 * 4 + 256;
    int* bucket = (int*)w; w += (size_t)RN * BCAP * 4;
    w = align_up(w, 16);
    __hip_bfloat16* WT = (__hip_bfloat16*)w; w += (size_t)DIM * KDIM * 2;
    w = align_up(w, 16);
    __hip_bfloat16* Y  = (__hip_bfloat16*)w; w += (size_t)Mpad * KMEAN * 2;
    __hip_bfloat16* xb = (__hip_bfloat16*)w; w += (size_t)Mpad * DIM * 2;

    hipMemsetAsync(counts, 0, zero_bytes, stream);

    int eb = (E + 255) / 256;                 // scatter / edge-weight blocks
    int n4 = N * DIM / 4;
    int cb = (n4 + 255) / 256;                // cast blocks
    int wb = (KDIM / 32) * (DIM / 32);        // W0-transpose blocks (40*8)

    prep<<<eb + cb + wb, 256, 0, stream>>>(etype, src, dst, counts, bucket, N, E,
                                           x, xb, n4, W0, root0, WT, eb, cb);

    int ab = (N + 1) / 2;
    // layer 0 aggregate (+ fused edge-weight pass for collapsed layer 1)
    aggregate<<<ab + eb, 256, 0, stream>>>(xb, counts, bucket, Y, N,
                                           etype, src, dst, wsr, E, ab);
    // layer 0 GEMM with fused layer-1 colsum epilogue -> sv  (626 blocks: m-blk x n-half)
    gemm_mfma<<<gx * 2, 256, 0, stream>>>(Y, xb, WT, b0, wsr, sv, N);
    // collapsed layer 1 GEMV + fused linear head -> out
    int gvb = KDIM / 8;
    gemv_final<<<gvb, 256, 0, stream>>>(sv, W1, root1, b1, N, g, done,
                                        lin_w, lin_b, out, gvb);
}